// Round 17
// baseline (275.838 us; speedup 1.0000x reference)
//
#include <hip/hip_runtime.h>
#include <hip/hip_bf16.h>

// Sizes: B=8, N=1024, hidden=256, H=4 heads, D=64, entity=31
typedef _Float16 f16x8 __attribute__((ext_vector_type(8)));
typedef float f32x4 __attribute__((ext_vector_type(4)));

// ---------------------------------------------------------------------------
__global__ __launch_bounds__(256) void k_proj(
    const float* __restrict__ agents, const int* __restrict__ my_id,
    const float* __restrict__ Wp, const float* __restrict__ bp,
    float* __restrict__ proj, float* __restrict__ mask, int* __restrict__ idx)
{
  int blk = blockIdx.x;
  int b = blk >> 10, n = blk & 1023;
  __shared__ float arow[32];
  int t = threadIdx.x;
  if (t < 31) arow[t] = agents[((size_t)(b * 1024 + n)) * 31 + t];
  __syncthreads();
  float id = arow[0];
  int npc = (int)arow[1];
  float acc = bp[t] + id * Wp[t] + Wp[(1 + npc) * 256 + t];
#pragma unroll
  for (int c = 2; c < 31; ++c) acc += arow[c] * Wp[(4 + c) * 256 + t];
  proj[((size_t)(b * 1024 + n)) * 256 + t] = acc;
  if (t == 0) {
    mask[b * 1024 + n] = (id != 0.f) ? 1.f : 0.f;
    if (id == (float)my_id[b]) atomicMin(&idx[b], n);
  }
}

// ---------------------------------------------------------------------------
// k_wt_all: transpose W1, W2, Wa in ONE launch (144 blocks).
__global__ __launch_bounds__(256) void k_wt_all(
    const float* __restrict__ W1, const float* __restrict__ W2,
    const float* __restrict__ Wa, float* __restrict__ Wt1,
    float* __restrict__ Wt2, float* __restrict__ Wta)
{
  __shared__ float tl[32][33];
  int blk = blockIdx.x;
  const float* W;
  float* Wt;
  int K;
  if (blk < 64)      { W = W1; Wt = Wt1; K = 256; }
  else if (blk < 128){ W = W2; Wt = Wt2; K = 256; blk -= 64; }
  else               { W = Wa; Wt = Wta; K = 64;  blk -= 128; }
  int bk = blk >> 3, bj = blk & 7;
  int tc = threadIdx.x & 31, tr = threadIdx.x >> 5;
#pragma unroll
  for (int r = 0; r < 4; ++r) {
    int row = tr * 4 + r;
    tl[row][tc] = W[(size_t)(bk * 32 + row) * 256 + bj * 32 + tc];
  }
  __syncthreads();
#pragma unroll
  for (int r = 0; r < 4; ++r) {
    int row = tr * 4 + r;
    Wt[(size_t)(bj * 32 + row) * K + bk * 32 + tc] = tl[tc][row];
  }
}

// ---------------------------------------------------------------------------
// k_gemm_mfma: C = A*B (+bias) via split-fp16 MFMA (verified R15, fp32-equiv).
// WRITE_HT: epilogue also writes hT fp16 chunk-tiled [b][h][c][64d][32j]
// (block bi,bj covers batch bi>>4, rows (bi&15)*64.., head bj -> 2 chunks),
// via LDS transpose tile, eliminating the separate k_prep pass.
template <int K, bool WRITE_HT>
__global__ __launch_bounds__(256) void k_gemm_mfma(
    const float* __restrict__ A, const float* __restrict__ BtF,
    const float* __restrict__ bias, float* __restrict__ C,
    _Float16* __restrict__ hT)
{
  __shared__ __align__(16) _Float16 AsH[64 * 40], AsL[64 * 40];
  __shared__ __align__(16) _Float16 BsH[64 * 40], BsL[64 * 40];
  __shared__ __align__(16) _Float16 tile[64][72];  // transpose staging (WRITE_HT)
  int t = threadIdx.x;
  int w = t >> 6, l = t & 63;
  int bi = blockIdx.x >> 2, bj = blockIdx.x & 3;
  int i0 = bi << 6, j0 = bj << 6;
  int srow = t >> 2, skq = (t & 3) << 3;

  f32x4 C0 = {0.f, 0.f, 0.f, 0.f}, C1 = C0, C2 = C0, C3 = C0;

  for (int k0 = 0; k0 < K; k0 += 32) {
    {
      const float* ap = A + (size_t)(i0 + srow) * K + k0 + skq;
      float4 a0 = *(const float4*)ap, a1 = *(const float4*)(ap + 4);
      float av[8] = {a0.x, a0.y, a0.z, a0.w, a1.x, a1.y, a1.z, a1.w};
      _Float16 hi[8], lo[8];
#pragma unroll
      for (int q = 0; q < 8; ++q) {
        hi[q] = (_Float16)av[q];
        lo[q] = (_Float16)(av[q] - (float)hi[q]);
      }
      *(uint4*)&AsH[srow * 40 + skq] = *(const uint4*)hi;
      *(uint4*)&AsL[srow * 40 + skq] = *(const uint4*)lo;
    }
    {
      const float* bp = BtF + (size_t)(j0 + srow) * K + k0 + skq;
      float4 b0 = *(const float4*)bp, b1 = *(const float4*)(bp + 4);
      float bv[8] = {b0.x, b0.y, b0.z, b0.w, b1.x, b1.y, b1.z, b1.w};
      _Float16 hi[8], lo[8];
#pragma unroll
      for (int q = 0; q < 8; ++q) {
        hi[q] = (_Float16)bv[q];
        lo[q] = (_Float16)(bv[q] - (float)hi[q]);
      }
      *(uint4*)&BsH[srow * 40 + skq] = *(const uint4*)hi;
      *(uint4*)&BsL[srow * 40 + skq] = *(const uint4*)lo;
    }
    __syncthreads();
    int fr = l & 15;
    int fk = (l >> 4) << 3;
    f16x8 ah = *(const f16x8*)&AsH[(w * 16 + fr) * 40 + fk];
    f16x8 al = *(const f16x8*)&AsL[(w * 16 + fr) * 40 + fk];
    {
      f16x8 bh = *(const f16x8*)&BsH[(0 * 16 + fr) * 40 + fk];
      f16x8 bl = *(const f16x8*)&BsL[(0 * 16 + fr) * 40 + fk];
      C0 = __builtin_amdgcn_mfma_f32_16x16x32_f16(ah, bh, C0, 0, 0, 0);
      C0 = __builtin_amdgcn_mfma_f32_16x16x32_f16(ah, bl, C0, 0, 0, 0);
      C0 = __builtin_amdgcn_mfma_f32_16x16x32_f16(al, bh, C0, 0, 0, 0);
    }
    {
      f16x8 bh = *(const f16x8*)&BsH[(1 * 16 + fr) * 40 + fk];
      f16x8 bl = *(const f16x8*)&BsL[(1 * 16 + fr) * 40 + fk];
      C1 = __builtin_amdgcn_mfma_f32_16x16x32_f16(ah, bh, C1, 0, 0, 0);
      C1 = __builtin_amdgcn_mfma_f32_16x16x32_f16(ah, bl, C1, 0, 0, 0);
      C1 = __builtin_amdgcn_mfma_f32_16x16x32_f16(al, bh, C1, 0, 0, 0);
    }
    {
      f16x8 bh = *(const f16x8*)&BsH[(2 * 16 + fr) * 40 + fk];
      f16x8 bl = *(const f16x8*)&BsL[(2 * 16 + fr) * 40 + fk];
      C2 = __builtin_amdgcn_mfma_f32_16x16x32_f16(ah, bh, C2, 0, 0, 0);
      C2 = __builtin_amdgcn_mfma_f32_16x16x32_f16(ah, bl, C2, 0, 0, 0);
      C2 = __builtin_amdgcn_mfma_f32_16x16x32_f16(al, bh, C2, 0, 0, 0);
    }
    {
      f16x8 bh = *(const f16x8*)&BsH[(3 * 16 + fr) * 40 + fk];
      f16x8 bl = *(const f16x8*)&BsL[(3 * 16 + fr) * 40 + fk];
      C3 = __builtin_amdgcn_mfma_f32_16x16x32_f16(ah, bh, C3, 0, 0, 0);
      C3 = __builtin_amdgcn_mfma_f32_16x16x32_f16(ah, bl, C3, 0, 0, 0);
      C3 = __builtin_amdgcn_mfma_f32_16x16x32_f16(al, bh, C3, 0, 0, 0);
    }
    __syncthreads();
  }

  // epilogue: C/D layout col = lane&15, row = (lane>>4)*4 + r  (m89)
  int rbase = i0 + w * 16 + ((l >> 4) << 2);
  int cb = j0 + (l & 15);
  float b0 = bias ? bias[cb] : 0.f;
  float b1 = bias ? bias[cb + 16] : 0.f;
  float b2 = bias ? bias[cb + 32] : 0.f;
  float b3 = bias ? bias[cb + 48] : 0.f;
#pragma unroll
  for (int r = 0; r < 4; ++r) {
    size_t ro = (size_t)(rbase + r) * 256;
    C[ro + cb]      = C0[r] + b0;
    C[ro + cb + 16] = C1[r] + b1;
    C[ro + cb + 32] = C2[r] + b2;
    C[ro + cb + 48] = C3[r] + b3;
  }

  if (WRITE_HT) {
    // stage fp16 transpose: tile[d][jloc]
    int jl = w * 16 + ((l >> 4) << 2);
    int d0 = l & 15;
#pragma unroll
    for (int r = 0; r < 4; ++r) {
      tile[d0][jl + r]      = (_Float16)C0[r];
      tile[d0 + 16][jl + r] = (_Float16)C1[r];
      tile[d0 + 32][jl + r] = (_Float16)C2[r];
      tile[d0 + 48][jl + r] = (_Float16)C3[r];
    }
    __syncthreads();
    // write hT[b][head=bj][c][d][32j]: thread -> (d = t>>2, cc = (t>>1)&1, gg = t&1)
    int d = t >> 2, cc = (t >> 1) & 1, gg = t & 1;
    int bb = bi >> 4;
    int c = ((bi & 15) << 1) + cc;
    _Float16* dst = hT + ((size_t)((bb * 4 + bj) * 32 + c)) * 2048 + d * 32 + gg * 16;
    const _Float16* srcp = &tile[d][cc * 32 + gg * 16];
    ((uint4*)dst)[0] = ((const uint4*)srcp)[0];
    ((uint4*)dst)[1] = ((const uint4*)srcp)[1];
  }
}

// ---------------------------------------------------------------------------
// k_edgemax: fused e_src/e_dst + masked max. One block per (b,head) = 32 blocks.
// 16-lane group = one row's 64 d (float4/lane); shfl_xor(1,2,4,8) reduce.
// Max over valid j is block-local (exact) -> Mmax[bh]; kills k_emax.
__global__ __launch_bounds__(256) void k_edgemax(
    const float* __restrict__ h, const float* __restrict__ a_src,
    const float* __restrict__ a_dst, const float* __restrict__ mask,
    float* __restrict__ esrc, float* __restrict__ edst, float* __restrict__ Mmax)
{
  int bh = blockIdx.x;
  int b = bh >> 2, hh = bh & 3;
  int t = threadIdx.x;
  int w = t >> 6, l = t & 63;
  int dq = (l & 15) << 2;
  int rloc = l >> 4;
  float4 as4 = *(const float4*)(a_src + hh * 64 + dq);
  float4 ad4 = *(const float4*)(a_dst + hh * 64 + dq);
  float mmax = -1e30f;
  for (int it = 0; it < 64; ++it) {
    int j = (w << 8) + (it << 2) + rloc;
    float4 hv = *(const float4*)(h + ((size_t)(b * 1024 + j)) * 256 + hh * 64 + dq);
    float ps = hv.x * as4.x + hv.y * as4.y + hv.z * as4.z + hv.w * as4.w;
    float pd = hv.x * ad4.x + hv.y * ad4.y + hv.z * ad4.z + hv.w * ad4.w;
#pragma unroll
    for (int o = 1; o < 16; o <<= 1) {
      ps += __shfl_xor(ps, o);
      pd += __shfl_xor(pd, o);
    }
    if ((l & 15) == 0) {
      esrc[(bh << 10) + j] = ps;
      edst[(bh << 10) + j] = pd;
    }
    if (mask[(b << 10) + j] != 0.f) mmax = fmaxf(mmax, pd);
  }
  mmax = fmaxf(mmax, __shfl_xor(mmax, 16));
  mmax = fmaxf(mmax, __shfl_xor(mmax, 32));
  __shared__ float red[4];
  if (l == 0) red[w] = mmax;
  __syncthreads();
  if (t == 0) Mmax[bh] = fmaxf(fmaxf(red[0], red[1]), fmaxf(red[2], red[3]));
}

// ---------------------------------------------------------------------------
// k_attn_mfma: P·h via mfma_f32_16x16x32_f16 (verified R14/R15, absmax 0.0078).
template <int LAYER>
__global__ __launch_bounds__(256) void k_attn_mfma(
    const _Float16* __restrict__ hT, const float* __restrict__ esrc,
    const float* __restrict__ edst, const float* __restrict__ Mmax,
    const float* __restrict__ mask, const float* __restrict__ resid,
    const float* __restrict__ g, const float* __restrict__ be,
    float* __restrict__ out)
{
  __shared__ __align__(16) char smem[40960];
  __shared__ float esrcL[16][4], mL[16][4];
  __shared__ float maskL[16], MhL[4];
  __shared__ float sInvS[4][16];
  __shared__ float statM[16], statR[16];

  int t = threadIdx.x;
  int hID = t >> 6, l = t & 63;
  int b = blockIdx.x & 7;
  int it = blockIdx.x >> 3;
  int i0 = it << 4;

  if (t < 16) maskL[t] = mask[(b << 10) + i0 + t];
  if (t < 4) MhL[t] = Mmax[(b << 2) + t];
  if (t < 64) {
    int ii = t >> 2, hh = t & 3;
    esrcL[ii][hh] = esrc[(((b << 2) + hh) << 10) + i0 + ii];
  }
  __syncthreads();
  if (t < 64) {
    int ii = t >> 2, hh = t & 3;
    float m = 0.f;
    if (maskL[ii] != 0.f) {
      float v = esrcL[ii][hh] + MhL[hh];
      m = v > 0.f ? v : 0.2f * v;
    }
    mL[ii][hh] = m;
  }
  __syncthreads();

  int iloc = l & 15;
  float esr = esrcL[iloc][hID];
  float mr = mL[iloc][hID];
  float mskI = maskL[iloc];
  int jg = (l >> 4) << 3;

  const float* ej_base = edst + (((b << 2) + hID) << 10);
  const float* mk_base = mask + (b << 10);
  const char* gT = (const char*)hT + ((size_t)((b * 4 + hID) * 32)) * 4096;
  char* hb = smem + hID * 10240;

  f32x4 C0 = {0.f,0.f,0.f,0.f}, C1 = C0, C2 = C0, C3 = C0;
  float sp = 0.f;

  {
    const uint4* gs = (const uint4*)(gT + l * 64);
    uint4 s0 = gs[0], s1 = gs[1], s2 = gs[2], s3 = gs[3];
    uint4* wp = (uint4*)(hb + l * 80);
    wp[0] = s0; wp[1] = s1; wp[2] = s2; wp[3] = s3;
  }
  int cur = 0;

  for (int c = 0; c < 32; ++c) {
    uint4 n0, n1, n2, n3;
    if (c < 31) {
      const uint4* gs = (const uint4*)(gT + (size_t)(c + 1) * 4096 + l * 64);
      n0 = gs[0]; n1 = gs[1]; n2 = gs[2]; n3 = gs[3];
    }
    int j0 = c << 5;
    float4 e0 = *(const float4*)(ej_base + j0 + jg);
    float4 e1 = *(const float4*)(ej_base + j0 + jg + 4);
    float4 m0 = *(const float4*)(mk_base + j0 + jg);
    float4 m1 = *(const float4*)(mk_base + j0 + jg + 4);
    float w[8];
    float ev[8] = {e0.x, e0.y, e0.z, e0.w, e1.x, e1.y, e1.z, e1.w};
    float mv[8] = {m0.x, m0.y, m0.z, m0.w, m1.x, m1.y, m1.z, m1.w};
    if (mskI != 0.f) {
#pragma unroll
      for (int q = 0; q < 8; ++q) {
        float v = esr + ev[q];
        v = v > 0.f ? v : 0.2f * v;
        w[q] = (mv[q] != 0.f) ? __expf(v - mr) : 0.f;
      }
    } else {
#pragma unroll
      for (int q = 0; q < 8; ++q) w[q] = 1.f;
    }
    f16x8 af;
#pragma unroll
    for (int q = 0; q < 8; ++q) { sp += w[q]; af[q] = (_Float16)w[q]; }
    const char* rp = hb + cur * 5120 + (l & 15) * 80 + (l >> 4) * 16;
    f16x8 b0 = *(const f16x8*)(rp);
    f16x8 b1 = *(const f16x8*)(rp + 1280);
    f16x8 b2 = *(const f16x8*)(rp + 2560);
    f16x8 b3 = *(const f16x8*)(rp + 3840);
    C0 = __builtin_amdgcn_mfma_f32_16x16x32_f16(af, b0, C0, 0, 0, 0);
    C1 = __builtin_amdgcn_mfma_f32_16x16x32_f16(af, b1, C1, 0, 0, 0);
    C2 = __builtin_amdgcn_mfma_f32_16x16x32_f16(af, b2, C2, 0, 0, 0);
    C3 = __builtin_amdgcn_mfma_f32_16x16x32_f16(af, b3, C3, 0, 0, 0);
    if (c < 31) {
      uint4* wp = (uint4*)(hb + (cur ^ 1) * 5120 + l * 80);
      wp[0] = n0; wp[1] = n1; wp[2] = n2; wp[3] = n3;
      cur ^= 1;
    }
  }

  sp += __shfl_xor(sp, 16);
  sp += __shfl_xor(sp, 32);
  if (l < 16) sInvS[hID][l] = 1.f / sp;
  __syncthreads();

  float (*y)[256] = (float (*)[256])smem;
  {
    int rbase = (l >> 4) << 2;
    int col = (hID << 6) + (l & 15);
#pragma unroll
    for (int r = 0; r < 4; ++r) {
      float sv = sInvS[hID][rbase + r];
      y[rbase + r][col +  0] = C0[r] * sv;
      y[rbase + r][col + 16] = C1[r] * sv;
      y[rbase + r][col + 32] = C2[r] * sv;
      y[rbase + r][col + 48] = C3[r] * sv;
    }
  }
  __syncthreads();

  if (LAYER == 1) {
#pragma unroll
    for (int i = 0; i < 16; ++i)
      y[i][t] += resid[((size_t)(b * 1024 + i0 + i)) * 256 + t];
    __syncthreads();
#pragma unroll
    for (int rr = 0; rr < 4; ++rr) {
      int i = (hID << 2) + rr;
      float v0 = y[i][l], v1 = y[i][64 + l], v2 = y[i][128 + l], v3 = y[i][192 + l];
      float s = v0 + v1 + v2 + v3;
      float q = v0 * v0 + v1 * v1 + v2 * v2 + v3 * v3;
      for (int o = 32; o; o >>= 1) { s += __shfl_xor(s, o); q += __shfl_xor(q, o); }
      if (l == 0) {
        float mean = s * (1.f / 256.f);
        float var = q * (1.f / 256.f) - mean * mean;
        statM[i] = mean;
        statR[i] = rsqrtf(var + 1e-5f);
      }
    }
    __syncthreads();
#pragma unroll
    for (int i = 0; i < 16; ++i) {
      float yv = y[i][t];
      float o_ = (yv - statM[i]) * statR[i] * g[t] + be[t];
      out[((size_t)(b * 1024 + i0 + i)) * 256 + t] = fmaxf(o_, 0.f);
    }
  } else {
#pragma unroll
    for (int rr = 0; rr < 4; ++rr) {
      int i = (hID << 2) + rr;
      float v = 0.25f * (y[i][l] + y[i][64 + l] + y[i][128 + l] + y[i][192 + l]);
      float s = v, q = v * v;
      for (int o = 32; o; o >>= 1) { s += __shfl_xor(s, o); q += __shfl_xor(q, o); }
      float mean = s * (1.f / 64.f);
      float var = q * (1.f / 64.f) - mean * mean;
      float rstd = rsqrtf(var + 1e-5f);
      float o_ = (v - mean) * rstd * g[l] + be[l];
      out[((size_t)(b * 1024 + i0 + i)) * 64 + l] = fmaxf(o_, 0.f);
    }
  }
}

// ---------------------------------------------------------------------------
__global__ __launch_bounds__(256) void k_myemb(
    const float* __restrict__ h2, const int* __restrict__ idx,
    const float* __restrict__ Wm, const float* __restrict__ bm, float* __restrict__ out)
{
  __shared__ float row[64];
  int t = threadIdx.x;
  for (int b = 0; b < 8; ++b) {
    int n = idx[b];
    if (t < 64) row[t] = h2[((size_t)(b * 1024 + n)) * 64 + t];
    __syncthreads();
    float acc = bm[t];
#pragma unroll
    for (int d = 0; d < 64; ++d) acc += row[d] * Wm[d * 256 + t];
    out[2097152 + b * 256 + t] = fmaxf(acc, 0.f);
    __syncthreads();
  }
}

// ---------------------------------------------------------------------------
extern "C" void kernel_launch(void* const* d_in, const int* in_sizes, int n_in,
                              void* d_out, int out_size, void* d_ws, size_t ws_size,
                              hipStream_t stream) {
  const float* agents = (const float*)d_in[0];
  const int* my_id = (const int*)d_in[1];
  const float* Wp = (const float*)d_in[2];
  const float* bp = (const float*)d_in[3];
  const float* W1 = (const float*)d_in[4];
  const float* a_src1 = (const float*)d_in[5];
  const float* a_dst1 = (const float*)d_in[6];
  const float* ln1_g = (const float*)d_in[7];
  const float* ln1_b = (const float*)d_in[8];
  const float* W2 = (const float*)d_in[9];
  const float* a_src2 = (const float*)d_in[10];
  const float* a_dst2 = (const float*)d_in[11];
  const float* ln2_g = (const float*)d_in[12];
  const float* ln2_b = (const float*)d_in[13];
  const float* Wa = (const float*)d_in[14];
  const float* ba = (const float*)d_in[15];
  const float* Wm = (const float*)d_in[16];
  const float* bm = (const float*)d_in[17];
  float* out = (float*)d_out;

  float* W = (float*)d_ws;
  float* mask = W;                    // 8192
  float* Mmax = W + 8192;             // 32
  int* idx = (int*)(W + 8224);        // 8 ints
  float* esrc = W + 16384;            // 32768  [B][H][N]
  float* edst = W + 49152;            // 32768
  float* proj = W + 81920;            // 2097152
  float* htmp = W + 2179072;          // 2097152
  float* h1 = W + 4276224;            // 2097152
  float* h2 = W + 6373376;            // 524288
  _Float16* hT = (_Float16*)(W + 6897664);  // 4 MB (2M halfs)
  float* Wt1 = W + 7946240;           // 65536  [256][256]
  float* Wt2 = W + 8011776;           // 65536
  float* Wta = W + 8077312;           // 16384  [256][64]

  hipMemsetAsync(idx, 0x7F, 8 * sizeof(int), stream);
  k_proj<<<8192, 256, 0, stream>>>(agents, my_id, Wp, bp, proj, mask, idx);
  k_wt_all<<<144, 256, 0, stream>>>(W1, W2, Wa, Wt1, Wt2, Wta);

  // ---- layer 1 ----
  k_gemm_mfma<256, true><<<512, 256, 0, stream>>>(proj, Wt1, nullptr, htmp, hT);
  k_edgemax<<<32, 256, 0, stream>>>(htmp, a_src1, a_dst1, mask, esrc, edst, Mmax);
  k_attn_mfma<1><<<512, 256, 0, stream>>>(hT, esrc, edst, Mmax, mask, proj, ln1_g, ln1_b, h1);

  // ---- layer 2 ----
  k_gemm_mfma<256, true><<<512, 256, 0, stream>>>(h1, Wt2, nullptr, htmp, hT);
  k_edgemax<<<32, 256, 0, stream>>>(htmp, a_src2, a_dst2, mask, esrc, edst, Mmax);
  k_attn_mfma<2><<<512, 256, 0, stream>>>(hT, esrc, edst, Mmax, mask, nullptr, ln2_g, ln2_b, h2);

  // ---- heads ----
  k_gemm_mfma<64, false><<<512, 256, 0, stream>>>(h2, Wta, ba, out, nullptr);
  k_myemb<<<1, 256, 0, stream>>>(h2, idx, Wm, bm, out);
}